// Round 3
// baseline (2763.782 us; speedup 1.0000x reference)
//
#include <hip/hip_runtime.h>
#include <hip/hip_bf16.h>

// Problem constants
#define BB 64      // batch
#define JJ 2048    // input capsules
#define DI 16      // input dim
#define CC 32      // output capsules
#define OO 32      // output dim
#define CO 1024    // CC*OO

// One routing pass: recompute u_hat tiles, logits from NPREV stored v's,
// softmax over c (wave-local shuffles), accumulate partial s per j-tile.
// Grid: NJT * 4 blocks. Block: 256 thr = 4 waves. Wave owns 4 b's; lane owns
// (c = lane&31, o-half = lane>>5) -> 16 (c,o) accumulators.
// Decode: jt = blockIdx % NJT, bq = blockIdx / NJT  => the 4 blocks sharing a
// jt have blockIdx stride NJT (multiple of 8) -> same XCD -> W j-slice is
// fetched into one XCD's L2 once.
template<int NPREV, int TJ, int NJT>
__global__ __launch_bounds__(256, 3) void route_pass(
    const float* __restrict__ X, const float* __restrict__ W,
    const float* __restrict__ vprev, float* __restrict__ partial)
{
  const int jt   = blockIdx.x & (NJT - 1);
  const int bq   = blockIdx.x >> (31 - __builtin_clz(NJT));  // blockIdx / NJT
  const int tid  = threadIdx.x;
  const int wave = tid >> 6;
  const int lane = tid & 63;
  const int c    = lane & 31;
  const int o0   = (lane >> 5) << 4;   // 0 or 16
  const int b0   = bq * 16 + wave * 4;

  float acc[4][16];
#pragma unroll
  for (int bl = 0; bl < 4; ++bl)
#pragma unroll
    for (int ol = 0; ol < 16; ++ol) acc[bl][ol] = 0.f;

  // W[c, j, o, i] flat: ((c*JJ + j)*OO + o)*DI + i  — lane's (c, o0..o0+15, :)
  // is 256 contiguous f32 per j.
  const float* wbase = W + ((size_t)c * JJ * OO + (size_t)o0) * DI;

  for (int jj = 0; jj < TJ; ++jj) {
    const int j = jt * TJ + jj;

    // x[b, j, :16] -> f32 regs for the wave's 4 b's (lane-invariant broadcast loads)
    float xf[4][16];
#pragma unroll
    for (int bl = 0; bl < 4; ++bl) {
      const float4* xp = (const float4*)(X + ((size_t)(b0 + bl) * JJ + j) * DI);
#pragma unroll
      for (int q = 0; q < 4; ++q) {
        float4 x4 = xp[q];
        xf[bl][4*q+0] = x4.x; xf[bl][4*q+1] = x4.y;
        xf[bl][4*q+2] = x4.z; xf[bl][4*q+3] = x4.w;
      }
    }

    const float4* wp = (const float4*)(wbase + (size_t)j * OO * DI);
    float t[4][16];   // u_hat values (only kept when NPREV>0)
#pragma unroll
    for (int ol = 0; ol < 16; ++ol) {
      float wf[16];
#pragma unroll
      for (int q = 0; q < 4; ++q) {
        float4 w4 = wp[4*ol + q];
        wf[4*q+0] = w4.x; wf[4*q+1] = w4.y;
        wf[4*q+2] = w4.z; wf[4*q+3] = w4.w;
      }
#pragma unroll
      for (int bl = 0; bl < 4; ++bl) {
        float tt = 0.f;
#pragma unroll
        for (int i = 0; i < 16; ++i) tt = fmaf(wf[i], xf[bl][i], tt);
        if (NPREV == 0) acc[bl][ol] += tt;   // coef uniform 1/32, scaled at the end
        else            t[bl][ol] = tt;
      }
    }

    if (NPREV > 0) {
#pragma unroll
      for (int bl = 0; bl < 4; ++bl) {
        // logit[b,c,j] = sum_{t<i} v_t[b,c,:] . u_hat[b,c,j,:]
        float dsum = 0.f;
#pragma unroll
        for (int n = 0; n < NPREV; ++n) {
          const float4* vp = (const float4*)(vprev + ((size_t)n * BB + (b0 + bl)) * CO
                                             + c * OO + o0);
#pragma unroll
          for (int q = 0; q < 4; ++q) {
            float4 v4 = vp[q];
            dsum = fmaf(v4.x, t[bl][4*q+0], dsum);
            dsum = fmaf(v4.y, t[bl][4*q+1], dsum);
            dsum = fmaf(v4.z, t[bl][4*q+2], dsum);
            dsum = fmaf(v4.w, t[bl][4*q+3], dsum);
          }
        }
        dsum += __shfl_xor(dsum, 32);           // combine the two o-halves
        // softmax over the 32 c's living in each 32-lane half
        float m = dsum;
#pragma unroll
        for (int s = 16; s >= 1; s >>= 1) m = fmaxf(m, __shfl_xor(m, s));
        float e = __expf(dsum - m);
        float den = e;
#pragma unroll
        for (int s = 16; s >= 1; s >>= 1) den += __shfl_xor(den, s);
        float coef = e / den;
#pragma unroll
        for (int ol = 0; ol < 16; ++ol)
          acc[bl][ol] = fmaf(coef, t[bl][ol], acc[bl][ol]);
      }
    }
  }

  const float cs = (NPREV == 0) ? 0.03125f : 1.f;
#pragma unroll
  for (int bl = 0; bl < 4; ++bl) {
    float* pp = partial + ((size_t)jt * BB + (b0 + bl)) * CO + c * OO + o0;
#pragma unroll
    for (int q = 0; q < 4; ++q) {
      float4 w4 = make_float4(acc[bl][4*q+0]*cs, acc[bl][4*q+1]*cs,
                              acc[bl][4*q+2]*cs, acc[bl][4*q+3]*cs);
      ((float4*)pp)[q] = w4;
    }
  }
}

// Sum the NJT j-tile partials -> s[b,c,o]; squash over o (32 lanes share a
// (b,c) row); write v_i (f32, for the next pass) and optionally the output.
template<int NJT>
__global__ __launch_bounds__(256, 1) void reduce_squash(
    const float* __restrict__ partial, float* __restrict__ vout,
    float* __restrict__ out, int last)
{
  const int idx = blockIdx.x * 256 + threadIdx.x;   // = b*CO + c*OO + o
  float s = 0.f;
#pragma unroll 8
  for (int nt = 0; nt < NJT; ++nt) s += partial[(size_t)nt * (BB * CO) + idx];
  float s2 = s * s;
#pragma unroll
  for (int m = 16; m >= 1; m >>= 1) s2 += __shfl_xor(s2, m);
  float scale = s2 / ((1.f + s2) * sqrtf(s2 + 1e-7f));
  float v = scale * s;
  vout[idx] = v;
  if (last) out[idx] = v;
}

template<int TJ, int NJT>
static void run_all(const float* X, const float* W, float* out,
                    void* d_ws, hipStream_t stream)
{
  float* partial = (float*)d_ws;                                 // NJT*64*1024 f32
  float* vbuf    = (float*)((char*)d_ws + (size_t)NJT*BB*CO*4);  // 3 * 64*1024 f32
  const int grid = NJT * 4;

  route_pass<0, TJ, NJT><<<grid, 256, 0, stream>>>(X, W, nullptr, partial);
  reduce_squash<NJT><<<BB*CO/256, 256, 0, stream>>>(partial, vbuf, nullptr, 0);

  route_pass<1, TJ, NJT><<<grid, 256, 0, stream>>>(X, W, vbuf, partial);
  reduce_squash<NJT><<<BB*CO/256, 256, 0, stream>>>(partial, vbuf + BB*CO, nullptr, 0);

  route_pass<2, TJ, NJT><<<grid, 256, 0, stream>>>(X, W, vbuf, partial);
  reduce_squash<NJT><<<BB*CO/256, 256, 0, stream>>>(partial, vbuf + 2*BB*CO, out, 1);
}

extern "C" void kernel_launch(void* const* d_in, const int* in_sizes, int n_in,
                              void* d_out, int out_size, void* d_ws, size_t ws_size,
                              hipStream_t stream) {
  (void)in_sizes; (void)n_in; (void)out_size;
  const float* X = (const float*)d_in[0];   // x [64,2048,16] f32
  const float* W = (const float*)d_in[1];   // W [32,2048,32,16] f32
  float* out = (float*)d_out;               // v [64,32,32] f32

  // Fast variant needs (256 + 3) * 64*1024 f32 = ~68 MB of workspace.
  const size_t need_big = (size_t)(256 + 3) * BB * CO * sizeof(float);
  if (ws_size >= need_big) {
    run_all<8, 256>(X, W, out, d_ws, stream);    // 1024 blocks: 3+ blocks/CU
  } else {
    run_all<32, 64>(X, W, out, d_ws, stream);    // proven-fit fallback
  }
}

// Round 4
// 1171.319 us; speedup vs baseline: 2.3595x; 2.3595x over previous
//
#include <hip/hip_runtime.h>
#include <hip/hip_bf16.h>

// Problem constants
#define BB 64      // batch
#define JJ 2048    // input capsules
#define DI 16      // input dim
#define CC 32      // output capsules
#define OO 32      // output dim
#define CO 1024    // CC*OO

// One routing pass: recompute u_hat tiles, logits from vsum = sum of previous
// v's (b_i = sum_{t<i} v_t . u_hat = vsum . u_hat), softmax over c via wave
// shuffles, accumulate partial s per j-tile.
// Grid: NJT * 4 blocks, 256 thr = 4 waves. Wave owns 4 b's; lane owns
// (c = lane&31, o-half = lane>>5) -> 16 (c,o) accumulators.
// Decode: jt = blockIdx % NJT, bq = blockIdx / NJT => same-jt blocks are
// blockIdx stride NJT (mult of 8) apart -> same XCD -> shared L2 W slice.
template<bool HAVE_V, int TJ, int NJT>
__global__ __launch_bounds__(256, 1) void route_pass(
    const float* __restrict__ X, const float* __restrict__ W,
    const float* __restrict__ vsum, float* __restrict__ partial)
{
  const int jt   = blockIdx.x & (NJT - 1);
  const int bq   = blockIdx.x >> (31 - __builtin_clz(NJT));  // blockIdx / NJT
  const int tid  = threadIdx.x;
  const int wave = tid >> 6;
  const int lane = tid & 63;
  const int c    = lane & 31;
  const int o0   = (lane >> 5) << 4;   // 0 or 16
  const int b0   = bq * 16 + wave * 4;

  float acc[4][16];
#pragma unroll
  for (int bl = 0; bl < 4; ++bl)
#pragma unroll
    for (int ol = 0; ol < 16; ++ol) acc[bl][ol] = 0.f;

  // W[c, j, o, i] flat: ((c*JJ + j)*OO + o)*DI + i  — lane's (c, o0..o0+15, :)
  // is 256 contiguous f32 per j.
  const float* wbase = W + ((size_t)c * JJ * OO + (size_t)o0) * DI;

  for (int jj = 0; jj < TJ; ++jj) {
    const int j = jt * TJ + jj;

    // x[b, j, :16] -> f32 regs for the wave's 4 b's (lane-invariant broadcast loads)
    float xf[4][16];
#pragma unroll
    for (int bl = 0; bl < 4; ++bl) {
      const float4* xp = (const float4*)(X + ((size_t)(b0 + bl) * JJ + j) * DI);
#pragma unroll
      for (int q = 0; q < 4; ++q) {
        float4 x4 = xp[q];
        xf[bl][4*q+0] = x4.x; xf[bl][4*q+1] = x4.y;
        xf[bl][4*q+2] = x4.z; xf[bl][4*q+3] = x4.w;
      }
    }

    const float4* wp = (const float4*)(wbase + (size_t)j * OO * DI);
    float t[4][16];   // u_hat values (only kept when HAVE_V)
#pragma unroll
    for (int ol = 0; ol < 16; ++ol) {
      float wf[16];
#pragma unroll
      for (int q = 0; q < 4; ++q) {
        float4 w4 = wp[4*ol + q];
        wf[4*q+0] = w4.x; wf[4*q+1] = w4.y;
        wf[4*q+2] = w4.z; wf[4*q+3] = w4.w;
      }
#pragma unroll
      for (int bl = 0; bl < 4; ++bl) {
        float tt = 0.f;
#pragma unroll
        for (int i = 0; i < 16; ++i) tt = fmaf(wf[i], xf[bl][i], tt);
        if (!HAVE_V) acc[bl][ol] += tt;   // coef uniform 1/32, scaled at the end
        else         t[bl][ol] = tt;
      }
    }

    if (HAVE_V) {
#pragma unroll
      for (int bl = 0; bl < 4; ++bl) {
        // logit[b,c,j] = vsum[b,c,:] . u_hat[b,c,j,:]
        float dsum = 0.f;
        const float4* vp = (const float4*)(vsum + (size_t)(b0 + bl) * CO
                                           + c * OO + o0);
#pragma unroll
        for (int q = 0; q < 4; ++q) {
          float4 v4 = vp[q];
          dsum = fmaf(v4.x, t[bl][4*q+0], dsum);
          dsum = fmaf(v4.y, t[bl][4*q+1], dsum);
          dsum = fmaf(v4.z, t[bl][4*q+2], dsum);
          dsum = fmaf(v4.w, t[bl][4*q+3], dsum);
        }
        dsum += __shfl_xor(dsum, 32);           // combine the two o-halves
        // softmax over the 32 c's living in each 32-lane half
        float m = dsum;
#pragma unroll
        for (int s = 16; s >= 1; s >>= 1) m = fmaxf(m, __shfl_xor(m, s));
        float e = __expf(dsum - m);
        float den = e;
#pragma unroll
        for (int s = 16; s >= 1; s >>= 1) den += __shfl_xor(den, s);
        float coef = e / den;
#pragma unroll
        for (int ol = 0; ol < 16; ++ol)
          acc[bl][ol] = fmaf(coef, t[bl][ol], acc[bl][ol]);
      }
    }
  }

  const float cs = HAVE_V ? 1.f : 0.03125f;
#pragma unroll
  for (int bl = 0; bl < 4; ++bl) {
    float* pp = partial + ((size_t)jt * BB + (b0 + bl)) * CO + c * OO + o0;
#pragma unroll
    for (int q = 0; q < 4; ++q) {
      float4 w4 = make_float4(acc[bl][4*q+0]*cs, acc[bl][4*q+1]*cs,
                              acc[bl][4*q+2]*cs, acc[bl][4*q+3]*cs);
      ((float4*)pp)[q] = w4;
    }
  }
}

// Sum the NJT j-tile partials -> s[b,c,o]; squash over o (32 lanes share a
// (b,c) row). Maintains vsum (running sum of v's) for the next routing pass,
// or writes the final output.
template<int NJT>
__global__ __launch_bounds__(256, 1) void reduce_squash(
    const float* __restrict__ partial, float* __restrict__ vsum,
    float* __restrict__ out, int mode)   // 0: vsum = v; 1: vsum += v; 2: out = v
{
  const int idx = blockIdx.x * 256 + threadIdx.x;   // = b*CO + c*OO + o
  float s = 0.f;
#pragma unroll 8
  for (int nt = 0; nt < NJT; ++nt) s += partial[(size_t)nt * (BB * CO) + idx];
  float s2 = s * s;
#pragma unroll
  for (int m = 16; m >= 1; m >>= 1) s2 += __shfl_xor(s2, m);
  float scale = s2 / ((1.f + s2) * sqrtf(s2 + 1e-7f));
  float v = scale * s;
  if (mode == 2)      out[idx] = v;
  else if (mode == 1) vsum[idx] += v;
  else                vsum[idx] = v;
}

template<int TJ, int NJT>
static void run_all(const float* X, const float* W, float* out,
                    void* d_ws, hipStream_t stream)
{
  float* partial = (float*)d_ws;                                 // NJT*64*1024 f32
  float* vsum    = (float*)((char*)d_ws + (size_t)NJT*BB*CO*4);  // 64*1024 f32
  const int grid = NJT * 4;
  const int rgrid = BB * CO / 256;

  route_pass<false, TJ, NJT><<<grid, 256, 0, stream>>>(X, W, nullptr, partial);
  reduce_squash<NJT><<<rgrid, 256, 0, stream>>>(partial, vsum, nullptr, 0);

  route_pass<true, TJ, NJT><<<grid, 256, 0, stream>>>(X, W, vsum, partial);
  reduce_squash<NJT><<<rgrid, 256, 0, stream>>>(partial, vsum, nullptr, 1);

  route_pass<true, TJ, NJT><<<grid, 256, 0, stream>>>(X, W, vsum, partial);
  reduce_squash<NJT><<<rgrid, 256, 0, stream>>>(partial, vsum, out, 2);
}

extern "C" void kernel_launch(void* const* d_in, const int* in_sizes, int n_in,
                              void* d_out, int out_size, void* d_ws, size_t ws_size,
                              hipStream_t stream) {
  (void)in_sizes; (void)n_in; (void)out_size;
  const float* X = (const float*)d_in[0];   // x [64,2048,16] f32
  const float* W = (const float*)d_in[1];   // W [32,2048,32,16] f32
  float* out = (float*)d_out;               // v [64,32,32] f32

  // Fast variant needs (256 + 1) * 64*1024 f32 = ~67.4 MB of workspace.
  const size_t need_big = (size_t)(256 + 1) * BB * CO * sizeof(float);
  if (ws_size >= need_big) {
    run_all<8, 256>(X, W, out, d_ws, stream);    // grid 1024: ~3 blocks/CU resident
  } else {
    run_all<32, 64>(X, W, out, d_ws, stream);    // small-ws fallback (grid 256)
  }
}

// Round 5
// 396.584 us; speedup vs baseline: 6.9690x; 2.9535x over previous
//
#include <hip/hip_runtime.h>
#include <hip/hip_bf16.h>
#include <stdint.h>

// Problem constants
#define BB 64      // batch
#define JJ 2048    // input capsules
#define DI 16      // input dim
#define CC 32      // output capsules
#define OO 32      // output dim
#define CO 1024    // CC*OO

static const size_t W2_BYTES = (size_t)CC * JJ * OO * DI * 2;  // 67108864
static const size_t X2_BYTES = (size_t)BB * JJ * DI * 2;       // 4194304

typedef _Float16 half2_t __attribute__((ext_vector_type(2)));

#if __has_builtin(__builtin_amdgcn_fdot2)
#define DOT2(a, b, c) __builtin_amdgcn_fdot2(__builtin_bit_cast(half2_t, (a)), \
                                             __builtin_bit_cast(half2_t, (b)), (c), false)
#else
__device__ __forceinline__ float dot2_sw(unsigned a, unsigned b, float c) {
  half2_t ha = __builtin_bit_cast(half2_t, a), hb = __builtin_bit_cast(half2_t, b);
  return fmaf((float)ha.x, (float)hb.x, fmaf((float)ha.y, (float)hb.y, c));
}
#define DOT2(a, b, c) dot2_sw((a), (b), (c))
#endif

union Pack8 { uint4 u; _Float16 h[8]; };

// W [c][j][o][i] f32 -> W2 [j][slot] f16 (16B blocks), slot = (ol*2+q)*64 + h*32 + c.
// This is the exact order route_f16's waves consume: at (ol,q) the 64 lanes
// (lane = h*32+c) read 64 consecutive 16B blocks -> coalesced staging AND
// conflict-free ds_read_b128 with zero swizzling.
__global__ __launch_bounds__(256) void prep_w(const float* __restrict__ W,
                                              uint4* __restrict__ W2) {
  const int j = blockIdx.x;    // 2048
  const int t = threadIdx.x;   // 256
#pragma unroll
  for (int r = 0; r < 8; ++r) {
    const int s = r * 256 + t;                       // 0..2047
    const int c = s & 31, h = (s >> 5) & 1, q = (s >> 6) & 1, ol = s >> 7;
    const float4* src = (const float4*)(W + ((((size_t)c * JJ + j) * OO + h * 16 + ol) * DI + q * 8));
    float4 a = src[0], b = src[1];
    Pack8 p;
    p.h[0] = (_Float16)a.x; p.h[1] = (_Float16)a.y; p.h[2] = (_Float16)a.z; p.h[3] = (_Float16)a.w;
    p.h[4] = (_Float16)b.x; p.h[5] = (_Float16)b.y; p.h[6] = (_Float16)b.z; p.h[7] = (_Float16)b.w;
    W2[(size_t)j * 2048 + s] = p.u;
  }
}

// X f32 -> f16, layout preserved [b][j][i].
__global__ __launch_bounds__(256) void prep_x(const float* __restrict__ X,
                                              uint4* __restrict__ X2) {
  const size_t t = (size_t)blockIdx.x * 256 + threadIdx.x;   // 262144 threads
  const float4* src = (const float4*)(X + t * 8);
  float4 a = src[0], b = src[1];
  Pack8 p;
  p.h[0] = (_Float16)a.x; p.h[1] = (_Float16)a.y; p.h[2] = (_Float16)a.z; p.h[3] = (_Float16)a.w;
  p.h[4] = (_Float16)b.x; p.h[5] = (_Float16)b.y; p.h[6] = (_Float16)b.z; p.h[7] = (_Float16)b.w;
  X2[t] = p.u;
}

// One routing pass, f16 operands, f32 math. Grid NJT*4 blocks of 256 (4 waves).
// Wave owns 4 b's; lane = h*32+c owns (c, o-half h) -> 16 (c,o) accumulators.
// Per j: async-stage next j's 32KB W slab into LDS (double-buffered) via
// global_load_lds while computing current j from LDS (ds_read_b128, dot2).
// Decode keeps all 4 bq-blocks of a jt on one XCD (stride NJT % 8 == 0).
template<bool HAVE_V, int TJ, int NJT, int LOG_NJT>
__global__ __launch_bounds__(256) void route_f16(
    const uint4* __restrict__ X2, const uint4* __restrict__ W2,
    const float* __restrict__ vsum, float* __restrict__ partial)
{
  __shared__ uint4 smem[2][2048];   // 2 x 32KB

  const int jt   = blockIdx.x & (NJT - 1);
  const int bq   = blockIdx.x >> LOG_NJT;
  const int tid  = threadIdx.x;
  const int wave = tid >> 6;
  const int lane = tid & 63;
  const int c    = lane & 31;
  const int h    = lane >> 5;
  const int b0   = bq * 16 + wave * 4;

  const uint4* wsrc = W2 + (size_t)jt * TJ * 2048;

  float acc[4][16];
#pragma unroll
  for (int bl = 0; bl < 4; ++bl)
#pragma unroll
    for (int ol = 0; ol < 16; ++ol) acc[bl][ol] = 0.f;

#define STAGE(buf, jj) do {                                                       \
    const uint4* sp_ = wsrc + (size_t)(jj) * 2048 + tid;                          \
    uint4* dp_ = &smem[buf][tid];                                                 \
    _Pragma("unroll")                                                             \
    for (int r_ = 0; r_ < 8; ++r_)                                                \
      __builtin_amdgcn_global_load_lds(                                           \
          (const __attribute__((address_space(1))) void*)(sp_ + r_ * 256),        \
          (__attribute__((address_space(3))) void*)(dp_ + r_ * 256), 16, 0, 0);   \
  } while (0)

  STAGE(0, 0);
  __syncthreads();   // drain DMA for j0

  for (int jj = 0; jj < TJ; ++jj) {
    const int buf = jj & 1;
    if (jj + 1 < TJ) STAGE(buf ^ 1, jj + 1);   // overlaps with compute below
    const int j = jt * TJ + jj;

    // x[b,j,:16] as 8 f16-pair dwords per b (lane-invariant broadcast loads)
    unsigned xp[4][8];
#pragma unroll
    for (int bl = 0; bl < 4; ++bl) {
      const uint4* xq = X2 + ((size_t)(b0 + bl) * JJ + j) * 2;
      uint4 x0 = xq[0], x1 = xq[1];
      xp[bl][0] = x0.x; xp[bl][1] = x0.y; xp[bl][2] = x0.z; xp[bl][3] = x0.w;
      xp[bl][4] = x1.x; xp[bl][5] = x1.y; xp[bl][6] = x1.z; xp[bl][7] = x1.w;
    }

    float uh[4][16];   // u_hat (kept only when HAVE_V)
#pragma unroll
    for (int ol = 0; ol < 16; ++ol) {
      uint4 w0 = smem[buf][(ol * 2 + 0) * 64 + lane];   // contiguous across lanes
      uint4 w1 = smem[buf][(ol * 2 + 1) * 64 + lane];
#pragma unroll
      for (int bl = 0; bl < 4; ++bl) {
        float s = 0.f;
        s = DOT2(w0.x, xp[bl][0], s); s = DOT2(w0.y, xp[bl][1], s);
        s = DOT2(w0.z, xp[bl][2], s); s = DOT2(w0.w, xp[bl][3], s);
        s = DOT2(w1.x, xp[bl][4], s); s = DOT2(w1.y, xp[bl][5], s);
        s = DOT2(w1.z, xp[bl][6], s); s = DOT2(w1.w, xp[bl][7], s);
        if (!HAVE_V) acc[bl][ol] += s;   // uniform coef 1/32 applied at the end
        else         uh[bl][ol] = s;
      }
    }

    if (HAVE_V) {
#pragma unroll
      for (int bl = 0; bl < 4; ++bl) {
        // logit[b,c,j] = vsum[b,c,:] . u_hat[b,c,j,:]
        float dsum = 0.f;
        const float4* vp = (const float4*)(vsum + (size_t)(b0 + bl) * CO + c * OO + h * 16);
#pragma unroll
        for (int q = 0; q < 4; ++q) {
          float4 v4 = vp[q];
          dsum = fmaf(v4.x, uh[bl][4 * q + 0], dsum);
          dsum = fmaf(v4.y, uh[bl][4 * q + 1], dsum);
          dsum = fmaf(v4.z, uh[bl][4 * q + 2], dsum);
          dsum = fmaf(v4.w, uh[bl][4 * q + 3], dsum);
        }
        dsum += __shfl_xor(dsum, 32);   // combine the two o-halves
        // softmax over the 32 c's within each 32-lane half
        float m = dsum;
#pragma unroll
        for (int s = 16; s >= 1; s >>= 1) m = fmaxf(m, __shfl_xor(m, s));
        float e = __expf(dsum - m);
        float den = e;
#pragma unroll
        for (int s = 16; s >= 1; s >>= 1) den += __shfl_xor(den, s);
        float coef = e / den;
#pragma unroll
        for (int ol = 0; ol < 16; ++ol)
          acc[bl][ol] = fmaf(coef, uh[bl][ol], acc[bl][ol]);
      }
    }

    __syncthreads();   // drains STAGE(jj+1) DMA; buf[cur] safe to overwrite next iter
  }
#undef STAGE

  const float cs = HAVE_V ? 1.f : 0.03125f;
#pragma unroll
  for (int bl = 0; bl < 4; ++bl) {
    float* pp = partial + ((size_t)jt * BB + (b0 + bl)) * CO + c * OO + h * 16;
#pragma unroll
    for (int q = 0; q < 4; ++q) {
      float4 w4 = make_float4(acc[bl][4 * q + 0] * cs, acc[bl][4 * q + 1] * cs,
                              acc[bl][4 * q + 2] * cs, acc[bl][4 * q + 3] * cs);
      ((float4*)pp)[q] = w4;
    }
  }
}

// ---------------- f32 fallback route (proven R2/R4 path) ----------------
template<bool HAVE_V, int TJ, int NJT>
__global__ __launch_bounds__(256, 1) void route_f32(
    const float* __restrict__ X, const float* __restrict__ W,
    const float* __restrict__ vsum, float* __restrict__ partial)
{
  const int jt   = blockIdx.x & (NJT - 1);
  const int bq   = blockIdx.x >> (31 - __builtin_clz(NJT));
  const int tid  = threadIdx.x;
  const int wave = tid >> 6;
  const int lane = tid & 63;
  const int c    = lane & 31;
  const int o0   = (lane >> 5) << 4;
  const int b0   = bq * 16 + wave * 4;

  float acc[4][16];
#pragma unroll
  for (int bl = 0; bl < 4; ++bl)
#pragma unroll
    for (int ol = 0; ol < 16; ++ol) acc[bl][ol] = 0.f;

  const float* wbase = W + ((size_t)c * JJ * OO + (size_t)o0) * DI;

  for (int jj = 0; jj < TJ; ++jj) {
    const int j = jt * TJ + jj;
    float xf[4][16];
#pragma unroll
    for (int bl = 0; bl < 4; ++bl) {
      const float4* xpt = (const float4*)(X + ((size_t)(b0 + bl) * JJ + j) * DI);
#pragma unroll
      for (int q = 0; q < 4; ++q) {
        float4 x4 = xpt[q];
        xf[bl][4*q+0] = x4.x; xf[bl][4*q+1] = x4.y;
        xf[bl][4*q+2] = x4.z; xf[bl][4*q+3] = x4.w;
      }
    }
    const float4* wp = (const float4*)(wbase + (size_t)j * OO * DI);
    float t[4][16];
#pragma unroll
    for (int ol = 0; ol < 16; ++ol) {
      float wf[16];
#pragma unroll
      for (int q = 0; q < 4; ++q) {
        float4 w4 = wp[4*ol + q];
        wf[4*q+0] = w4.x; wf[4*q+1] = w4.y;
        wf[4*q+2] = w4.z; wf[4*q+3] = w4.w;
      }
#pragma unroll
      for (int bl = 0; bl < 4; ++bl) {
        float tt = 0.f;
#pragma unroll
        for (int i = 0; i < 16; ++i) tt = fmaf(wf[i], xf[bl][i], tt);
        if (!HAVE_V) acc[bl][ol] += tt;
        else         t[bl][ol] = tt;
      }
    }
    if (HAVE_V) {
#pragma unroll
      for (int bl = 0; bl < 4; ++bl) {
        float dsum = 0.f;
        const float4* vp = (const float4*)(vsum + (size_t)(b0 + bl) * CO + c * OO + o0);
#pragma unroll
        for (int q = 0; q < 4; ++q) {
          float4 v4 = vp[q];
          dsum = fmaf(v4.x, t[bl][4*q+0], dsum);
          dsum = fmaf(v4.y, t[bl][4*q+1], dsum);
          dsum = fmaf(v4.z, t[bl][4*q+2], dsum);
          dsum = fmaf(v4.w, t[bl][4*q+3], dsum);
        }
        dsum += __shfl_xor(dsum, 32);
        float m = dsum;
#pragma unroll
        for (int s = 16; s >= 1; s >>= 1) m = fmaxf(m, __shfl_xor(m, s));
        float e = __expf(dsum - m);
        float den = e;
#pragma unroll
        for (int s = 16; s >= 1; s >>= 1) den += __shfl_xor(den, s);
        float coef = e / den;
#pragma unroll
        for (int ol = 0; ol < 16; ++ol)
          acc[bl][ol] = fmaf(coef, t[bl][ol], acc[bl][ol]);
      }
    }
  }
  const float cs = HAVE_V ? 1.f : 0.03125f;
#pragma unroll
  for (int bl = 0; bl < 4; ++bl) {
    float* pp = partial + ((size_t)jt * BB + (b0 + bl)) * CO + c * OO + o0;
#pragma unroll
    for (int q = 0; q < 4; ++q) {
      float4 w4 = make_float4(acc[bl][4*q+0]*cs, acc[bl][4*q+1]*cs,
                              acc[bl][4*q+2]*cs, acc[bl][4*q+3]*cs);
      ((float4*)pp)[q] = w4;
    }
  }
}

// Sum NJT j-tile partials -> s[b,c,o]; squash over o; maintain vsum / write out.
template<int NJT>
__global__ __launch_bounds__(256, 1) void reduce_squash(
    const float* __restrict__ partial, float* __restrict__ vsum,
    float* __restrict__ out, int mode)   // 0: vsum = v; 1: vsum += v; 2: out = v
{
  const int idx = blockIdx.x * 256 + threadIdx.x;   // = b*CO + c*OO + o
  float s0 = 0.f, s1 = 0.f, s2 = 0.f, s3 = 0.f;
#pragma unroll 4
  for (int nt = 0; nt < NJT; nt += 4) {
    s0 += partial[(size_t)(nt + 0) * (BB * CO) + idx];
    s1 += partial[(size_t)(nt + 1) * (BB * CO) + idx];
    s2 += partial[(size_t)(nt + 2) * (BB * CO) + idx];
    s3 += partial[(size_t)(nt + 3) * (BB * CO) + idx];
  }
  float s = (s0 + s1) + (s2 + s3);
  float s2m = s * s;
#pragma unroll
  for (int m = 16; m >= 1; m >>= 1) s2m += __shfl_xor(s2m, m);
  float scale = s2m / ((1.f + s2m) * sqrtf(s2m + 1e-7f));
  float v = scale * s;
  if (mode == 2)      out[idx] = v;
  else if (mode == 1) vsum[idx] += v;
  else                vsum[idx] = v;
}

template<int TJ, int NJT, int LOG_NJT>
static void run_f16(const float* X, const float* W, float* out,
                    void* d_ws, hipStream_t stream)
{
  uint4* W2      = (uint4*)d_ws;
  uint4* X2      = (uint4*)((char*)d_ws + W2_BYTES);
  float* partial = (float*)((char*)d_ws + W2_BYTES + X2_BYTES);
  float* vsum    = partial + (size_t)NJT * BB * CO;
  const int grid  = NJT * 4;
  const int rgrid = BB * CO / 256;

  prep_w<<<JJ, 256, 0, stream>>>(W, W2);
  prep_x<<<(BB * JJ * DI / 8) / 256, 256, 0, stream>>>(X, X2);

  route_f16<false, TJ, NJT, LOG_NJT><<<grid, 256, 0, stream>>>(X2, W2, nullptr, partial);
  reduce_squash<NJT><<<rgrid, 256, 0, stream>>>(partial, vsum, nullptr, 0);

  route_f16<true, TJ, NJT, LOG_NJT><<<grid, 256, 0, stream>>>(X2, W2, vsum, partial);
  reduce_squash<NJT><<<rgrid, 256, 0, stream>>>(partial, vsum, nullptr, 1);

  route_f16<true, TJ, NJT, LOG_NJT><<<grid, 256, 0, stream>>>(X2, W2, vsum, partial);
  reduce_squash<NJT><<<rgrid, 256, 0, stream>>>(partial, vsum, out, 2);
}

static void run_f32_fallback(const float* X, const float* W, float* out,
                             void* d_ws, hipStream_t stream)
{
  const int NJT = 64, TJ = 32;
  float* partial = (float*)d_ws;
  float* vsum    = partial + (size_t)NJT * BB * CO;
  const int grid  = NJT * 4;
  const int rgrid = BB * CO / 256;

  route_f32<false, 32, 64><<<grid, 256, 0, stream>>>(X, W, nullptr, partial);
  reduce_squash<64><<<rgrid, 256, 0, stream>>>(partial, vsum, nullptr, 0);
  route_f32<true, 32, 64><<<grid, 256, 0, stream>>>(X, W, vsum, partial);
  reduce_squash<64><<<rgrid, 256, 0, stream>>>(partial, vsum, nullptr, 1);
  route_f32<true, 32, 64><<<grid, 256, 0, stream>>>(X, W, vsum, partial);
  reduce_squash<64><<<rgrid, 256, 0, stream>>>(partial, vsum, out, 2);
}

extern "C" void kernel_launch(void* const* d_in, const int* in_sizes, int n_in,
                              void* d_out, int out_size, void* d_ws, size_t ws_size,
                              hipStream_t stream) {
  (void)in_sizes; (void)n_in; (void)out_size;
  const float* X = (const float*)d_in[0];   // x [64,2048,16] f32
  const float* W = (const float*)d_in[1];   // W [32,2048,32,16] f32
  float* out = (float*)d_out;               // v [64,32,32] f32

  const size_t need16 = W2_BYTES + X2_BYTES + (size_t)128 * BB * CO * 4 + (size_t)BB * CO * 4;
  const size_t need32 = W2_BYTES + X2_BYTES + (size_t)64  * BB * CO * 4 + (size_t)BB * CO * 4;

  if (ws_size >= need16)       run_f16<16, 128, 7>(X, W, out, d_ws, stream);
  else if (ws_size >= need32)  run_f16<32, 64, 6>(X, W, out, d_ws, stream);
  else                         run_f32_fallback(X, W, out, d_ws, stream);
}

// Round 6
// 346.654 us; speedup vs baseline: 7.9727x; 1.1440x over previous
//
#include <hip/hip_runtime.h>
#include <hip/hip_bf16.h>
#include <stdint.h>

// Problem constants
#define BB 64      // batch
#define JJ 2048    // input capsules
#define DI 16      // input dim
#define CC 32      // output capsules
#define OO 32      // output dim
#define CO 1024    // CC*OO

static const size_t W2_BYTES = (size_t)CC * JJ * OO * DI * 2;  // 67108864
static const size_t X2_BYTES = (size_t)BB * JJ * DI * 2;       // 4194304

typedef _Float16 half2_t __attribute__((ext_vector_type(2)));

#if __has_builtin(__builtin_amdgcn_fdot2)
#define DOT2(a, b, c) __builtin_amdgcn_fdot2(__builtin_bit_cast(half2_t, (a)), \
                                             __builtin_bit_cast(half2_t, (b)), (c), false)
#else
__device__ __forceinline__ float dot2_sw(unsigned a, unsigned b, float c) {
  half2_t ha = __builtin_bit_cast(half2_t, a), hb = __builtin_bit_cast(half2_t, b);
  return fmaf((float)ha.x, (float)hb.x, fmaf((float)ha.y, (float)hb.y, c));
}
#define DOT2(a, b, c) dot2_sw((a), (b), (c))
#endif

union Pack8 { uint4 u; _Float16 h[8]; };

// W [c][j][o][i] f32 -> W2 [j][slot] f16 (16B blocks), slot = (ol*2+q)*64 + h*32 + c.
// Exactly the order route kernels consume: at (ol,q) the 64 lanes (lane=h*32+c)
// read 64 consecutive 16B blocks -> coalesced staging, conflict-free ds_read_b128.
__global__ __launch_bounds__(256) void prep_w(const float* __restrict__ W,
                                              uint4* __restrict__ W2) {
  const int j = blockIdx.x;    // 2048
  const int t = threadIdx.x;   // 256
#pragma unroll
  for (int r = 0; r < 8; ++r) {
    const int s = r * 256 + t;                       // 0..2047
    const int c = s & 31, h = (s >> 5) & 1, q = (s >> 6) & 1, ol = s >> 7;
    const float4* src = (const float4*)(W + ((((size_t)c * JJ + j) * OO + h * 16 + ol) * DI + q * 8));
    float4 a = src[0], b = src[1];
    Pack8 p;
    p.h[0] = (_Float16)a.x; p.h[1] = (_Float16)a.y; p.h[2] = (_Float16)a.z; p.h[3] = (_Float16)a.w;
    p.h[4] = (_Float16)b.x; p.h[5] = (_Float16)b.y; p.h[6] = (_Float16)b.z; p.h[7] = (_Float16)b.w;
    W2[(size_t)j * 2048 + s] = p.u;
  }
}

// X f32 -> f16, layout preserved [b][j][i].
__global__ __launch_bounds__(256) void prep_x(const float* __restrict__ X,
                                              uint4* __restrict__ X2) {
  const size_t t = (size_t)blockIdx.x * 256 + threadIdx.x;
  const float4* src = (const float4*)(X + t * 8);
  float4 a = src[0], b = src[1];
  Pack8 p;
  p.h[0] = (_Float16)a.x; p.h[1] = (_Float16)a.y; p.h[2] = (_Float16)a.z; p.h[3] = (_Float16)a.w;
  p.h[4] = (_Float16)b.x; p.h[5] = (_Float16)b.y; p.h[6] = (_Float16)b.z; p.h[7] = (_Float16)b.w;
  X2[t] = p.u;
}

// ---------------- pipelined route: 512 thr (8 waves), 1 block/CU ----------------
// grid = 128 jt * 2 bq = 256 blocks. Wave owns 4 b's (b0 = bq*32 + wave*4).
// lane = h*32 + c. Depth-2 DMA prefetch, 3 LDS W-buffers, counted vmcnt(4),
// raw s_barrier (no vmcnt(0) drain in the loop). x staged in LDS at prologue
// so loop VMEM = STAGE only (exact vmcnt accounting). vsum hoisted to regs.
#define TJP 16
#define NJTP 128
template<bool HAVE_V>
__global__ __launch_bounds__(512, 2) void route_pipe(
    const uint4* __restrict__ X2, const uint4* __restrict__ W2,
    const float* __restrict__ vsum, float* __restrict__ partial)
{
  __shared__ uint4 wbuf[3][2048];   // 3 x 32KB
  __shared__ uint4 xbuf[1024];      // 16KB: x[b_local][jj] 32B blocks

  const int jt   = blockIdx.x & (NJTP - 1);
  const int bq   = blockIdx.x >> 7;
  const int tid  = threadIdx.x;
  const int wave = tid >> 6;
  const int lane = tid & 63;
  const int c    = lane & 31;
  const int h    = lane >> 5;
  const int b0   = bq * 32 + wave * 4;

  const uint4* wsrc = W2 + (size_t)jt * TJP * 2048;

  // vsum[b0+bl][c][h*16..+16] -> regs (j-invariant)
  float4 vs[4][4];
  if (HAVE_V) {
#pragma unroll
    for (int bl = 0; bl < 4; ++bl) {
      const float4* vp = (const float4*)(vsum + (size_t)(b0 + bl) * CO + c * OO + h * 16);
#pragma unroll
      for (int q = 0; q < 4; ++q) vs[bl][q] = vp[q];
    }
  }

#define STAGEW(bufidx, slab) do {                                                 \
    const uint4* sp_ = wsrc + (size_t)(slab) * 2048 + tid;                        \
    uint4* dp_ = &wbuf[bufidx][tid];                                              \
    _Pragma("unroll")                                                             \
    for (int r_ = 0; r_ < 4; ++r_)                                                \
      __builtin_amdgcn_global_load_lds(                                           \
          (const __attribute__((address_space(1))) void*)(sp_ + r_ * 512),        \
          (__attribute__((address_space(3))) void*)(dp_ + r_ * 512), 16, 0, 0);   \
  } while (0)

  // stage x tile: thread t, instr r covers LDS bytes r*8192 + t*16
  // = b_local*512 + jj*32 + half*16 with b=16r+(t>>5), jj=(t&31)>>1, half=t&1.
#pragma unroll
  for (int r = 0; r < 2; ++r) {
    const int bl_ = 16 * r + (tid >> 5);
    const int jjx = (tid & 31) >> 1;
    const int hf  = tid & 1;
    const uint4* src = X2 + ((size_t)(bq * 32 + bl_) * JJ + (jt * TJP + jjx)) * 2 + hf;
    __builtin_amdgcn_global_load_lds(
        (const __attribute__((address_space(1))) void*)src,
        (__attribute__((address_space(3))) void*)&xbuf[r * 512 + tid], 16, 0, 0);
  }
  STAGEW(0, 0);
  STAGEW(1, 1);

  float acc[4][16];
#pragma unroll
  for (int bl = 0; bl < 4; ++bl)
#pragma unroll
    for (int ol = 0; ol < 16; ++ol) acc[bl][ol] = 0.f;

  int bcur = 0;
  for (int jj = 0; jj < TJP; ++jj) {
    // Wait: current slab landed (oldest beyond 4 done => only slab jj+1 may
    // remain in flight); drain own LDS reads before barrier (3-buffer safety).
    if (jj == TJP - 1) asm volatile("s_waitcnt vmcnt(0) lgkmcnt(0)" ::: "memory");
    else               asm volatile("s_waitcnt vmcnt(4) lgkmcnt(0)" ::: "memory");
    __builtin_amdgcn_s_barrier();
    if (jj + 2 < TJP) {
      const int bstg = (bcur == 0) ? 2 : bcur - 1;   // (jj+2) % 3
      STAGEW(bstg, jj + 2);
    }

    const uint4* wb = wbuf[bcur];

    // x[b,jj,:16] from LDS (uniform-per-wave broadcast reads)
    unsigned xp[4][8];
#pragma unroll
    for (int bl = 0; bl < 4; ++bl) {
      uint4 x0 = xbuf[(wave * 4 + bl) * 32 + jj * 2];
      uint4 x1 = xbuf[(wave * 4 + bl) * 32 + jj * 2 + 1];
      xp[bl][0] = x0.x; xp[bl][1] = x0.y; xp[bl][2] = x0.z; xp[bl][3] = x0.w;
      xp[bl][4] = x1.x; xp[bl][5] = x1.y; xp[bl][6] = x1.z; xp[bl][7] = x1.w;
    }

    float uh[4][16];
#pragma unroll
    for (int ol = 0; ol < 16; ++ol) {
      uint4 w0 = wb[(ol * 2 + 0) * 64 + lane];
      uint4 w1 = wb[(ol * 2 + 1) * 64 + lane];
#pragma unroll
      for (int bl = 0; bl < 4; ++bl) {
        float s = 0.f;
        s = DOT2(w0.x, xp[bl][0], s); s = DOT2(w0.y, xp[bl][1], s);
        s = DOT2(w0.z, xp[bl][2], s); s = DOT2(w0.w, xp[bl][3], s);
        s = DOT2(w1.x, xp[bl][4], s); s = DOT2(w1.y, xp[bl][5], s);
        s = DOT2(w1.z, xp[bl][6], s); s = DOT2(w1.w, xp[bl][7], s);
        if (!HAVE_V) acc[bl][ol] += s;   // uniform coef 1/32 applied at end
        else         uh[bl][ol] = s;
      }
    }

    if (HAVE_V) {
#pragma unroll
      for (int bl = 0; bl < 4; ++bl) {
        float dsum = 0.f;
#pragma unroll
        for (int q = 0; q < 4; ++q) {
          float4 v4 = vs[bl][q];
          dsum = fmaf(v4.x, uh[bl][4 * q + 0], dsum);
          dsum = fmaf(v4.y, uh[bl][4 * q + 1], dsum);
          dsum = fmaf(v4.z, uh[bl][4 * q + 2], dsum);
          dsum = fmaf(v4.w, uh[bl][4 * q + 3], dsum);
        }
        dsum += __shfl_xor(dsum, 32);   // combine o-halves
        float m = dsum;
#pragma unroll
        for (int s = 16; s >= 1; s >>= 1) m = fmaxf(m, __shfl_xor(m, s));
        float e = __expf(dsum - m);
        float den = e;
#pragma unroll
        for (int s = 16; s >= 1; s >>= 1) den += __shfl_xor(den, s);
        float coef = e / den;
#pragma unroll
        for (int ol = 0; ol < 16; ++ol)
          acc[bl][ol] = fmaf(coef, uh[bl][ol], acc[bl][ol]);
      }
    }

    bcur = (bcur == 2) ? 0 : bcur + 1;
  }
#undef STAGEW

  const float cs = HAVE_V ? 1.f : 0.03125f;
#pragma unroll
  for (int bl = 0; bl < 4; ++bl) {
    float* pp = partial + ((size_t)jt * BB + (b0 + bl)) * CO + c * OO + h * 16;
#pragma unroll
    for (int q = 0; q < 4; ++q) {
      float4 w4 = make_float4(acc[bl][4 * q + 0] * cs, acc[bl][4 * q + 1] * cs,
                              acc[bl][4 * q + 2] * cs, acc[bl][4 * q + 3] * cs);
      ((float4*)pp)[q] = w4;
    }
  }
}

// ---------------- f32 fallback route (proven R2/R4 path) ----------------
template<bool HAVE_V, int TJ, int NJT>
__global__ __launch_bounds__(256, 1) void route_f32(
    const float* __restrict__ X, const float* __restrict__ W,
    const float* __restrict__ vsum, float* __restrict__ partial)
{
  const int jt   = blockIdx.x & (NJT - 1);
  const int bq   = blockIdx.x >> (31 - __builtin_clz(NJT));
  const int tid  = threadIdx.x;
  const int wave = tid >> 6;
  const int lane = tid & 63;
  const int c    = lane & 31;
  const int o0   = (lane >> 5) << 4;
  const int b0   = bq * 16 + wave * 4;

  float acc[4][16];
#pragma unroll
  for (int bl = 0; bl < 4; ++bl)
#pragma unroll
    for (int ol = 0; ol < 16; ++ol) acc[bl][ol] = 0.f;

  const float* wbase = W + ((size_t)c * JJ * OO + (size_t)o0) * DI;

  for (int jj = 0; jj < TJ; ++jj) {
    const int j = jt * TJ + jj;
    float xf[4][16];
#pragma unroll
    for (int bl = 0; bl < 4; ++bl) {
      const float4* xpt = (const float4*)(X + ((size_t)(b0 + bl) * JJ + j) * DI);
#pragma unroll
      for (int q = 0; q < 4; ++q) {
        float4 x4 = xpt[q];
        xf[bl][4*q+0] = x4.x; xf[bl][4*q+1] = x4.y;
        xf[bl][4*q+2] = x4.z; xf[bl][4*q+3] = x4.w;
      }
    }
    const float4* wp = (const float4*)(wbase + (size_t)j * OO * DI);
    float t[4][16];
#pragma unroll
    for (int ol = 0; ol < 16; ++ol) {
      float wf[16];
#pragma unroll
      for (int q = 0; q < 4; ++q) {
        float4 w4 = wp[4*ol + q];
        wf[4*q+0] = w4.x; wf[4*q+1] = w4.y;
        wf[4*q+2] = w4.z; wf[4*q+3] = w4.w;
      }
#pragma unroll
      for (int bl = 0; bl < 4; ++bl) {
        float tt = 0.f;
#pragma unroll
        for (int i = 0; i < 16; ++i) tt = fmaf(wf[i], xf[bl][i], tt);
        if (!HAVE_V) acc[bl][ol] += tt;
        else         t[bl][ol] = tt;
      }
    }
    if (HAVE_V) {
#pragma unroll
      for (int bl = 0; bl < 4; ++bl) {
        float dsum = 0.f;
        const float4* vp = (const float4*)(vsum + (size_t)(b0 + bl) * CO + c * OO + o0);
#pragma unroll
        for (int q = 0; q < 4; ++q) {
          float4 v4 = vp[q];
          dsum = fmaf(v4.x, t[bl][4*q+0], dsum);
          dsum = fmaf(v4.y, t[bl][4*q+1], dsum);
          dsum = fmaf(v4.z, t[bl][4*q+2], dsum);
          dsum = fmaf(v4.w, t[bl][4*q+3], dsum);
        }
        dsum += __shfl_xor(dsum, 32);
        float m = dsum;
#pragma unroll
        for (int s = 16; s >= 1; s >>= 1) m = fmaxf(m, __shfl_xor(m, s));
        float e = __expf(dsum - m);
        float den = e;
#pragma unroll
        for (int s = 16; s >= 1; s >>= 1) den += __shfl_xor(den, s);
        float coef = e / den;
#pragma unroll
        for (int ol = 0; ol < 16; ++ol)
          acc[bl][ol] = fmaf(coef, t[bl][ol], acc[bl][ol]);
      }
    }
  }
  const float cs = HAVE_V ? 1.f : 0.03125f;
#pragma unroll
  for (int bl = 0; bl < 4; ++bl) {
    float* pp = partial + ((size_t)jt * BB + (b0 + bl)) * CO + c * OO + o0;
#pragma unroll
    for (int q = 0; q < 4; ++q) {
      float4 w4 = make_float4(acc[bl][4*q+0]*cs, acc[bl][4*q+1]*cs,
                              acc[bl][4*q+2]*cs, acc[bl][4*q+3]*cs);
      ((float4*)pp)[q] = w4;
    }
  }
}

// Sum NJT j-tile partials -> s[b,c,o]; squash over o; maintain vsum / write out.
template<int NJT>
__global__ __launch_bounds__(256, 1) void reduce_squash(
    const float* __restrict__ partial, float* __restrict__ vsum,
    float* __restrict__ out, int mode)   // 0: vsum = v; 1: vsum += v; 2: out = v
{
  const int idx = blockIdx.x * 256 + threadIdx.x;   // = b*CO + c*OO + o
  float s0 = 0.f, s1 = 0.f, s2 = 0.f, s3 = 0.f;
#pragma unroll 4
  for (int nt = 0; nt < NJT; nt += 4) {
    s0 += partial[(size_t)(nt + 0) * (BB * CO) + idx];
    s1 += partial[(size_t)(nt + 1) * (BB * CO) + idx];
    s2 += partial[(size_t)(nt + 2) * (BB * CO) + idx];
    s3 += partial[(size_t)(nt + 3) * (BB * CO) + idx];
  }
  float s = (s0 + s1) + (s2 + s3);
  float s2m = s * s;
#pragma unroll
  for (int m = 16; m >= 1; m >>= 1) s2m += __shfl_xor(s2m, m);
  float scale = s2m / ((1.f + s2m) * sqrtf(s2m + 1e-7f));
  float v = scale * s;
  if (mode == 2)      out[idx] = v;
  else if (mode == 1) vsum[idx] += v;
  else                vsum[idx] = v;
}

static void run_pipe(const float* X, const float* W, float* out,
                     void* d_ws, hipStream_t stream)
{
  uint4* W2      = (uint4*)d_ws;
  uint4* X2      = (uint4*)((char*)d_ws + W2_BYTES);
  float* partial = (float*)((char*)d_ws + W2_BYTES + X2_BYTES);
  float* vsum    = partial + (size_t)NJTP * BB * CO;
  const int grid  = NJTP * 2;        // 256 blocks of 512
  const int rgrid = BB * CO / 256;

  prep_w<<<JJ, 256, 0, stream>>>(W, W2);
  prep_x<<<(BB * JJ * DI / 8) / 256, 256, 0, stream>>>(X, X2);

  route_pipe<false><<<grid, 512, 0, stream>>>(X2, W2, nullptr, partial);
  reduce_squash<NJTP><<<rgrid, 256, 0, stream>>>(partial, vsum, nullptr, 0);

  route_pipe<true><<<grid, 512, 0, stream>>>(X2, W2, vsum, partial);
  reduce_squash<NJTP><<<rgrid, 256, 0, stream>>>(partial, vsum, nullptr, 1);

  route_pipe<true><<<grid, 512, 0, stream>>>(X2, W2, vsum, partial);
  reduce_squash<NJTP><<<rgrid, 256, 0, stream>>>(partial, vsum, out, 2);
}

static void run_f32_fallback(const float* X, const float* W, float* out,
                             void* d_ws, hipStream_t stream)
{
  float* partial = (float*)d_ws;
  float* vsum    = partial + (size_t)64 * BB * CO;
  const int grid  = 64 * 4;
  const int rgrid = BB * CO / 256;

  route_f32<false, 32, 64><<<grid, 256, 0, stream>>>(X, W, nullptr, partial);
  reduce_squash<64><<<rgrid, 256, 0, stream>>>(partial, vsum, nullptr, 0);
  route_f32<true, 32, 64><<<grid, 256, 0, stream>>>(X, W, vsum, partial);
  reduce_squash<64><<<rgrid, 256, 0, stream>>>(partial, vsum, nullptr, 1);
  route_f32<true, 32, 64><<<grid, 256, 0, stream>>>(X, W, vsum, partial);
  reduce_squash<64><<<rgrid, 256, 0, stream>>>(partial, vsum, out, 2);
}

extern "C" void kernel_launch(void* const* d_in, const int* in_sizes, int n_in,
                              void* d_out, int out_size, void* d_ws, size_t ws_size,
                              hipStream_t stream) {
  (void)in_sizes; (void)n_in; (void)out_size;
  const float* X = (const float*)d_in[0];   // x [64,2048,16] f32
  const float* W = (const float*)d_in[1];   // W [32,2048,32,16] f32
  float* out = (float*)d_out;               // v [64,32,32] f32

  const size_t need_pipe = W2_BYTES + X2_BYTES
                         + (size_t)NJTP * BB * CO * 4 + (size_t)BB * CO * 4;
  if (ws_size >= need_pipe) run_pipe(X, W, out, d_ws, stream);
  else                      run_f32_fallback(X, W, out, d_ws, stream);
}

// Round 8
// 323.826 us; speedup vs baseline: 8.5348x; 1.0705x over previous
//
#include <hip/hip_runtime.h>
#include <hip/hip_bf16.h>
#include <stdint.h>

// Problem constants
#define BB 64      // batch
#define JJ 2048    // input capsules
#define DI 16      // input dim
#define CC 32      // output capsules
#define OO 32      // output dim
#define CO 1024    // CC*OO
#define TJ 16      // j per block
#define NJT 128    // JJ/TJ

static const size_t W2_BYTES = (size_t)CC * JJ * OO * DI * 2;  // 64 MB
static const size_t X3_BYTES = (size_t)2 * JJ * 2 * 64 * 16;   // 4 MB (bq, j, m, lane)

typedef _Float16 f16x4 __attribute__((ext_vector_type(4)));
typedef float    f32x4 __attribute__((ext_vector_type(4)));

// __has_builtin on amdgcn target builtins is FALSE in the host pass (R7 lesson);
// gate on device compile and give the host a parse-only dummy.
#if defined(__HIP_DEVICE_COMPILE__)
# if __has_builtin(__builtin_amdgcn_mfma_f32_16x16x16f16)
#  define MFMA16(a, b, c) __builtin_amdgcn_mfma_f32_16x16x16f16((a), (b), (c), 0, 0, 0)
# else
#  define MFMA16(a, b, c) __builtin_amdgcn_mfma_f32_16x16x16_f16((a), (b), (c), 0, 0, 0)
# endif
#else
# define MFMA16(a, b, c) (c)
#endif

union Pack8 { uint4 u; _Float16 h[8]; };

// W [c][j][o][i] f32 -> W2 [j][p][lane][f][e] f16: B-fragment consumption order.
// Fragment B for n-tile n: lane l supplies B[k = 4*(l>>4)+e][col = l&15], i.e.
// W[co = n*16 + (l&15)][i = 4*(l>>4)+e]. Pair n = 2p, 2p+1 per 16B so the route
// kernel reads one ds_read_b128 per n-pair.
__global__ __launch_bounds__(256) void prep_w(const float* __restrict__ W,
                                              uint4* __restrict__ W2) {
  const int j = blockIdx.x;    // 2048
  const int tt = threadIdx.x;  // 256
#pragma unroll
  for (int r = 0; r < 8; ++r) {
    const int s = r * 256 + tt;            // 0..2047
    const int p = s >> 6, l = s & 63;
    Pack8 pk;
#pragma unroll
    for (int f = 0; f < 2; ++f) {
      const int co = (2 * p + f) * 16 + (l & 15);
      const int c = co >> 5, o = co & 31;
      const float4 src = ((const float4*)W)[(((size_t)c * JJ + j) * OO + o) * 4 + (l >> 4)];
      pk.h[f * 4 + 0] = (_Float16)src.x;
      pk.h[f * 4 + 1] = (_Float16)src.y;
      pk.h[f * 4 + 2] = (_Float16)src.z;
      pk.h[f * 4 + 3] = (_Float16)src.w;
    }
    W2[(size_t)j * 2048 + s] = pk.u;
  }
}

// x [b][j][i] f32 -> X3 [bq][j][m][lane] f16: A-fragment consumption order.
// Fragment A for M-tile m: lane l supplies A[row = l&15][k = 4*(l>>4)+e], i.e.
// x[b = bq*32 + m*16 + (l&15)][j][i = 4*(l>>4)+e].
__global__ __launch_bounds__(256) void prep_x(const float* __restrict__ X,
                                              uint4* __restrict__ X3) {
  const unsigned T = blockIdx.x * 256 + threadIdx.x;   // 262144
  const int k = T & 31, m = (T >> 5) & 1, j = (T >> 6) & 2047, bq = (int)(T >> 17);
  Pack8 pk;
#pragma unroll
  for (int half = 0; half < 2; ++half) {
    const int l = 2 * k + half;
    const int b = bq * 32 + m * 16 + (l & 15);
    const float4 src = ((const float4*)X)[((size_t)b * JJ + j) * 4 + (l >> 4)];
    pk.h[half * 4 + 0] = (_Float16)src.x;
    pk.h[half * 4 + 1] = (_Float16)src.y;
    pk.h[half * 4 + 2] = (_Float16)src.z;
    pk.h[half * 4 + 3] = (_Float16)src.w;
  }
  X3[T] = pk.u;
}

// MFMA routing pass. Grid = NJT*2 blocks of 1024 (16 waves), 1 block/CU.
// Block covers 32 b (bq half) x 1024 co x TJ j. Wave w: m = w&1 (16-b M-tile),
// nb = w>>1 (8 n-tiles = 4 c's). Per j: 8 MFMA/wave; logits via uh.vs +
// 16-lane shuffle reduce; block softmax through padded lbuf; s accumulated in
// MFMA C/D layout. DMA: 3-slab triple-buffer, depth-2 prefetch, counted
// vmcnt(2) (never 0 mid-loop), raw s_barrier with lgkmcnt-only waits.
template<bool HAVE_V>
__global__ __launch_bounds__(1024, 1) void route_mfma(
    const uint4* __restrict__ X3, const uint4* __restrict__ W2,
    const float* __restrict__ vsum, float* __restrict__ partial)
{
  __shared__ uint4 wbuf[3][2048];   // 3 x 32KB W slabs
  __shared__ uint4 xbuf[1024];      // 16KB: A-frags for 16 j x 2 m
  __shared__ float lbuf[32 * 33];   // logits/coef, +1 pad row stride

  const int jt   = blockIdx.x & (NJT - 1);
  const int bq   = blockIdx.x >> 7;
  const int tid  = threadIdx.x;
  const int w    = tid >> 6;
  const int lane = tid & 63;
  const int g    = lane >> 4;
  const int t    = lane & 15;
  const int m    = w & 1;
  const int nb   = w >> 1;

  // vs[nl][r] = vsum[b(g,r)][c(nl)][o(nl,t)]  (j-invariant, 32 VGPR)
  float vs[8][4];
  if (HAVE_V) {
#pragma unroll
    for (int nl = 0; nl < 8; ++nl) {
      const int c = nb * 4 + (nl >> 1);
      const int o = (nl & 1) * 16 + t;
#pragma unroll
      for (int r = 0; r < 4; ++r) {
        const int b = bq * 32 + m * 16 + 4 * g + r;
        vs[nl][r] = vsum[(size_t)b * CO + c * OO + o];
      }
    }
  }

  const uint4* wsrc = W2 + (size_t)jt * TJ * 2048;

#define STAGEW(bufidx, slab) do {                                                 \
    const uint4* sp_ = wsrc + (size_t)(slab) * 2048 + tid;                        \
    uint4* dp_ = &wbuf[bufidx][tid];                                              \
    _Pragma("unroll")                                                             \
    for (int r_ = 0; r_ < 2; ++r_)                                                \
      __builtin_amdgcn_global_load_lds(                                           \
          (const __attribute__((address_space(1))) void*)(sp_ + r_ * 1024),       \
          (__attribute__((address_space(3))) void*)(dp_ + r_ * 1024), 16, 0, 0);  \
  } while (0)

  // prologue: x A-frags (16 KB, 1 instr) + first two W slabs
  {
    const uint4* xs = X3 + ((size_t)bq * JJ + jt * TJ) * 64 + tid;
    __builtin_amdgcn_global_load_lds(
        (const __attribute__((address_space(1))) void*)xs,
        (__attribute__((address_space(3))) void*)&xbuf[tid], 16, 0, 0);
  }
  STAGEW(0, 0);
  STAGEW(1, 1);

  f32x4 acc[8];
#pragma unroll
  for (int n = 0; n < 8; ++n) acc[n] = f32x4{0.f, 0.f, 0.f, 0.f};

  int bcur = 0;
  for (int jj = 0; jj < TJ; ++jj) {
    // slab jj landed (leave the 2 newest = slab jj+1 in flight); prior-j LDS ops done
    if (jj == TJ - 1) asm volatile("s_waitcnt vmcnt(0) lgkmcnt(0)" ::: "memory");
    else              asm volatile("s_waitcnt vmcnt(2) lgkmcnt(0)" ::: "memory");
    __builtin_amdgcn_s_barrier();
    if (jj + 2 < TJ) {
      const int bstg = (bcur == 0) ? 2 : bcur - 1;   // (jj+2) % 3
      STAGEW(bstg, jj + 2);
    }

    // A fragment (ds_read_b64)
    const uint2* xb = (const uint2*)xbuf;
    uint2 av = xb[jj * 128 + m * 64 + lane];
    f16x4 a = __builtin_bit_cast(f16x4, av);

    // B fragments (4x ds_read_b128 = 8 n-tiles) + MFMA
    f32x4 uh[8];
#pragma unroll
    for (int p = 0; p < 4; ++p) {
      uint4 wv = wbuf[bcur][(nb * 4 + p) * 64 + lane];
      f16x4 b0 = __builtin_bit_cast(f16x4, make_uint2(wv.x, wv.y));
      f16x4 b1 = __builtin_bit_cast(f16x4, make_uint2(wv.z, wv.w));
      if (HAVE_V) {
        uh[2 * p]     = MFMA16(a, b0, (f32x4{0.f, 0.f, 0.f, 0.f}));
        uh[2 * p + 1] = MFMA16(a, b1, (f32x4{0.f, 0.f, 0.f, 0.f}));
      } else {
        acc[2 * p]     = MFMA16(a, b0, acc[2 * p]);
        acc[2 * p + 1] = MFMA16(a, b1, acc[2 * p + 1]);
      }
    }

    if (HAVE_V) {
      // logit partials lp[r][cl]: dot over this lane's two o's
      float lp[4][4];
#pragma unroll
      for (int r = 0; r < 4; ++r)
#pragma unroll
        for (int cl = 0; cl < 4; ++cl)
          lp[r][cl] = fmaf(uh[2 * cl][r], vs[2 * cl][r],
                           uh[2 * cl + 1][r] * vs[2 * cl + 1][r]);
      // reduce over the 16 t-lanes (o dimension)
#pragma unroll
      for (int r = 0; r < 4; ++r)
#pragma unroll
        for (int cl = 0; cl < 4; ++cl) {
          float v = lp[r][cl];
          v += __shfl_xor(v, 1); v += __shfl_xor(v, 2);
          v += __shfl_xor(v, 4); v += __shfl_xor(v, 8);
          lp[r][cl] = v;
        }
      if (t == 0) {
#pragma unroll
        for (int r = 0; r < 4; ++r)
#pragma unroll
          for (int cl = 0; cl < 4; ++cl)
            lbuf[(m * 16 + 4 * g + r) * 33 + nb * 4 + cl] = lp[r][cl];
      }
      asm volatile("s_waitcnt lgkmcnt(0)" ::: "memory");
      __builtin_amdgcn_s_barrier();

      // softmax over c: wave w owns rows 2w, 2w+1 (lanes: c = lane&31)
      {
        const int row = 2 * w + (lane >> 5);
        const int cc  = lane & 31;
        float lg = lbuf[row * 33 + cc];
        float mx = lg;
        mx = fmaxf(mx, __shfl_xor(mx, 16)); mx = fmaxf(mx, __shfl_xor(mx, 8));
        mx = fmaxf(mx, __shfl_xor(mx, 4));  mx = fmaxf(mx, __shfl_xor(mx, 2));
        mx = fmaxf(mx, __shfl_xor(mx, 1));
        float e = __expf(lg - mx);
        float den = e;
        den += __shfl_xor(den, 16); den += __shfl_xor(den, 8);
        den += __shfl_xor(den, 4);  den += __shfl_xor(den, 2);
        den += __shfl_xor(den, 1);
        lbuf[row * 33 + cc] = e / den;
      }
      asm volatile("s_waitcnt lgkmcnt(0)" ::: "memory");
      __builtin_amdgcn_s_barrier();

      // s accumulate: acc[n][r] += coef[b(g,r)][c(n)] * uh[n][r]
#pragma unroll
      for (int p = 0; p < 4; ++p)
#pragma unroll
        for (int r = 0; r < 4; ++r) {
          const float cf = lbuf[(m * 16 + 4 * g + r) * 33 + nb * 4 + p];
          acc[2 * p][r]     = fmaf(cf, uh[2 * p][r],     acc[2 * p][r]);
          acc[2 * p + 1][r] = fmaf(cf, uh[2 * p + 1][r], acc[2 * p + 1][r]);
        }
    }
    bcur = (bcur == 2) ? 0 : bcur + 1;
  }
#undef STAGEW

  // C/D layout (m89): lane holds col = lane&15 -> our B-col co = n*16 + t;
  // row = 4*(lane>>4) + r -> our A-row b-offset 4g + r.
  const float cs = HAVE_V ? 1.f : 0.03125f;
#pragma unroll
  for (int nl = 0; nl < 8; ++nl) {
    const int co = (nb * 8 + nl) * 16 + t;
#pragma unroll
    for (int r = 0; r < 4; ++r) {
      const int b = bq * 32 + m * 16 + 4 * g + r;
      partial[((size_t)jt * BB + b) * CO + co] = acc[nl][r] * cs;
    }
  }
}

// ---------------- f32 fallback route (proven R2/R4 path) ----------------
template<bool HAVE_V>
__global__ __launch_bounds__(256, 1) void route_f32(
    const float* __restrict__ X, const float* __restrict__ W,
    const float* __restrict__ vsum, float* __restrict__ partial)
{
  const int jt   = blockIdx.x & 63;
  const int bq   = blockIdx.x >> 6;
  const int tid  = threadIdx.x;
  const int wave = tid >> 6;
  const int lane = tid & 63;
  const int c    = lane & 31;
  const int o0   = (lane >> 5) << 4;
  const int b0   = bq * 16 + wave * 4;

  float acc[4][16];
#pragma unroll
  for (int bl = 0; bl < 4; ++bl)
#pragma unroll
    for (int ol = 0; ol < 16; ++ol) acc[bl][ol] = 0.f;

  const float* wbase = W + ((size_t)c * JJ * OO + (size_t)o0) * DI;

  for (int jj = 0; jj < 32; ++jj) {
    const int j = jt * 32 + jj;
    float xf[4][16];
#pragma unroll
    for (int bl = 0; bl < 4; ++bl) {
      const float4* xpt = (const float4*)(X + ((size_t)(b0 + bl) * JJ + j) * DI);
#pragma unroll
      for (int q = 0; q < 4; ++q) {
        float4 x4 = xpt[q];
        xf[bl][4*q+0] = x4.x; xf[bl][4*q+1] = x4.y;
        xf[bl][4*q+2] = x4.z; xf[bl][4*q+3] = x4.w;
      }
    }
    const float4* wp = (const float4*)(wbase + (size_t)j * OO * DI);
    float tv[4][16];
#pragma unroll
    for (int ol = 0; ol < 16; ++ol) {
      float wf[16];
#pragma unroll
      for (int q = 0; q < 4; ++q) {
        float4 w4 = wp[4*ol + q];
        wf[4*q+0] = w4.x; wf[4*q+1] = w4.y;
        wf[4*q+2] = w4.z; wf[4*q+3] = w4.w;
      }
#pragma unroll
      for (int bl = 0; bl < 4; ++bl) {
        float tt = 0.f;
#pragma unroll
        for (int i = 0; i < 16; ++i) tt = fmaf(wf[i], xf[bl][i], tt);
        if (!HAVE_V) acc[bl][ol] += tt;
        else         tv[bl][ol] = tt;
      }
    }
    if (HAVE_V) {
#pragma unroll
      for (int bl = 0; bl < 4; ++bl) {
        float dsum = 0.f;
        const float4* vp = (const float4*)(vsum + (size_t)(b0 + bl) * CO + c * OO + o0);
#pragma unroll
        for (int q = 0; q < 4; ++q) {
          float4 v4 = vp[q];
          dsum = fmaf(v4.x, tv[bl][4*q+0], dsum);
          dsum = fmaf(v4.y, tv[bl][4*q+1], dsum);
          dsum = fmaf(v4.z, tv[bl][4*q+2], dsum);
          dsum = fmaf(v4.w, tv[bl][4*q+3], dsum);
        }
        dsum += __shfl_xor(dsum, 32);
        float mm = dsum;
#pragma unroll
        for (int s = 16; s >= 1; s >>= 1) mm = fmaxf(mm, __shfl_xor(mm, s));
        float e = __expf(dsum - mm);
        float den = e;
#pragma unroll
        for (int s = 16; s >= 1; s >>= 1) den += __shfl_xor(den, s);
        float coef = e / den;
#pragma unroll
        for (int ol = 0; ol < 16; ++ol)
          acc[bl][ol] = fmaf(coef, tv[bl][ol], acc[bl][ol]);
      }
    }
  }
  const float cs = HAVE_V ? 1.f : 0.03125f;
#pragma unroll
  for (int bl = 0; bl < 4; ++bl) {
    float* pp = partial + ((size_t)jt * BB + (b0 + bl)) * CO + c * OO + o0;
#pragma unroll
    for (int q = 0; q < 4; ++q) {
      float4 w4 = make_float4(acc[bl][4*q+0]*cs, acc[bl][4*q+1]*cs,
                              acc[bl][4*q+2]*cs, acc[bl][4*q+3]*cs);
      ((float4*)pp)[q] = w4;
    }
  }
}

// Sum NJT j-tile partials -> s[b,c,o]; squash over o; maintain vsum / write out.
template<int NJTR>
__global__ __launch_bounds__(256, 1) void reduce_squash(
    const float* __restrict__ partial, float* __restrict__ vsum,
    float* __restrict__ out, int mode)   // 0: vsum = v; 1: vsum += v; 2: out = v
{
  const int idx = blockIdx.x * 256 + threadIdx.x;   // = b*CO + c*OO + o
  float s0 = 0.f, s1 = 0.f, s2 = 0.f, s3 = 0.f;
#pragma unroll 4
  for (int nt = 0; nt < NJTR; nt += 4) {
    s0 += partial[(size_t)(nt + 0) * (BB * CO) + idx];
    s1 += partial[(size_t)(nt + 1) * (BB * CO) + idx];
    s2 += partial[(size_t)(nt + 2) * (BB * CO) + idx];
    s3 += partial[(size_t)(nt + 3) * (BB * CO) + idx];
  }
  float s = (s0 + s1) + (s2 + s3);
  float s2m = s * s;
#pragma unroll
  for (int mk = 16; mk >= 1; mk >>= 1) s2m += __shfl_xor(s2m, mk);
  float scale = s2m / ((1.f + s2m) * sqrtf(s2m + 1e-7f));
  float v = scale * s;
  if (mode == 2)      out[idx] = v;
  else if (mode == 1) vsum[idx] += v;
  else                vsum[idx] = v;
}

static void run_mfma(const float* X, const float* W, float* out,
                     void* d_ws, hipStream_t stream)
{
  uint4* W2      = (uint4*)d_ws;
  uint4* X3      = (uint4*)((char*)d_ws + W2_BYTES);
  float* partial = (float*)((char*)d_ws + W2_BYTES + X3_BYTES);
  float* vsum    = partial + (size_t)NJT * BB * CO;
  const int grid  = NJT * 2;         // 256 blocks of 1024
  const int rgrid = BB * CO / 256;

  prep_w<<<JJ, 256, 0, stream>>>(W, W2);
  prep_x<<<1024, 256, 0, stream>>>(X, X3);

  route_mfma<false><<<grid, 1024, 0, stream>>>(X3, W2, nullptr, partial);
  reduce_squash<NJT><<<rgrid, 256, 0, stream>>>(partial, vsum, nullptr, 0);

  route_mfma<true><<<grid, 1024, 0, stream>>>(X3, W2, vsum, partial);
  reduce_squash<NJT><<<rgrid, 256, 0, stream>>>(partial, vsum, nullptr, 1);

  route_mfma<true><<<grid, 1024, 0, stream>>>(X3, W2, vsum, partial);
  reduce_squash<NJT><<<rgrid, 256, 0, stream>>>(partial, vsum, out, 2);
}

static void run_f32_fallback(const float* X, const float* W, float* out,
                             void* d_ws, hipStream_t stream)
{
  float* partial = (float*)d_ws;
  float* vsum    = partial + (size_t)64 * BB * CO;
  const int grid  = 64 * 4;
  const int rgrid = BB * CO / 256;

  route_f32<false><<<grid, 256, 0, stream>>>(X, W, nullptr, partial);
  reduce_squash<64><<<rgrid, 256, 0, stream>>>(partial, vsum, nullptr, 0);
  route_f32<true><<<grid, 256, 0, stream>>>(X, W, vsum, partial);
  reduce_squash<64><<<rgrid, 256, 0, stream>>>(partial, vsum, nullptr, 1);
  route_f32<true><<<grid, 256, 0, stream>>>(X, W, vsum, partial);
  reduce_squash<64><<<rgrid, 256, 0, stream>>>(partial, vsum, out, 2);
}

extern "C" void kernel_launch(void* const* d_in, const int* in_sizes, int n_in,
                              void* d_out, int out_size, void* d_ws, size_t ws_size,
                              hipStream_t stream) {
  (void)in_sizes; (void)n_in; (void)out_size;
  const float* X = (const float*)d_in[0];   // x [64,2048,16] f32
  const float* W = (const float*)d_in[1];   // W [32,2048,32,16] f32
  float* out = (float*)d_out;               // v [64,32,32] f32

  const size_t need = W2_BYTES + X3_BYTES
                    + (size_t)NJT * BB * CO * 4 + (size_t)BB * CO * 4;
  if (ws_size >= need) run_mfma(X, W, out, d_ws, stream);
  else                 run_f32_fallback(X, W, out, d_ws, stream);
}

// Round 9
// 187.340 us; speedup vs baseline: 14.7528x; 1.7285x over previous
//
#include <hip/hip_runtime.h>
#include <hip/hip_bf16.h>
#include <stdint.h>

// Problem constants
#define BB 64      // batch
#define JJ 2048    // input capsules
#define DI 16      // input dim
#define CC 32      // output capsules
#define OO 32      // output dim
#define CO 1024    // CC*OO
#define TJ 16      // j per block
#define NJT 128    // JJ/TJ

static const size_t W2_BYTES = (size_t)CC * JJ * OO * DI * 2;  // 64 MB
static const size_t X3_BYTES = (size_t)BB * JJ * DI * 2;       // 4 MB

typedef _Float16 f16x4 __attribute__((ext_vector_type(4)));
typedef float    f32x4 __attribute__((ext_vector_type(4)));

// __has_builtin on amdgcn builtins is false in the host pass (R7 lesson).
#if defined(__HIP_DEVICE_COMPILE__)
# if __has_builtin(__builtin_amdgcn_mfma_f32_16x16x16f16)
#  define MFMA16(a, b, c) __builtin_amdgcn_mfma_f32_16x16x16f16((a), (b), (c), 0, 0, 0)
# else
#  define MFMA16(a, b, c) __builtin_amdgcn_mfma_f32_16x16x16_f16((a), (b), (c), 0, 0, 0)
# endif
# define SCHED_FENCE() __builtin_amdgcn_sched_barrier(0)
#else
# define MFMA16(a, b, c) (c)
# define SCHED_FENCE()
#endif

union Pack8 { uint4 u; _Float16 h[8]; };
union Pack2 { unsigned u; _Float16 h[2]; };

// W [c][j][o][i] f32 -> W2 f16 in A-fragment order (A = W, rows = co, k = i):
// entry E = (j*64 + ct)*64 + l holds, for e=0..3, W[co = ct*16 + (l&15)]
// [i = 4*(l>>4)+e] of column j. 8B per (E); stored as 16B pairs.
__global__ __launch_bounds__(256) void prep_w(const float* __restrict__ W,
                                              uint2* __restrict__ W2) {
  const int j = blockIdx.x;    // 2048
  const int tt = threadIdx.x;  // 256
#pragma unroll
  for (int r = 0; r < 16; ++r) {
    const int s = r * 256 + tt;           // 0..4095 = ct*64 + l
    const int ct = s >> 6, l = s & 63;
    const int co = ct * 16 + (l & 15);
    const int c = co >> 5, o = co & 31;
    const float4 src = ((const float4*)W)[(((size_t)c * JJ + j) * OO + o) * 4 + (l >> 4)];
    Pack2 a, b;
    a.h[0] = (_Float16)src.x; a.h[1] = (_Float16)src.y;
    b.h[0] = (_Float16)src.z; b.h[1] = (_Float16)src.w;
    W2[(size_t)j * 4096 + s] = make_uint2(a.u, b.u);
  }
}

// x [b][j][i] f32 -> X3 f16 in B-fragment order (B = x, cols = b, k = i):
// entry E = ((bq*JJ + j)*2 + bt)*64 + l holds x[b = bq*32 + bt*16 + (l&15)]
// [i = 4*(l>>4)+e], e=0..3.
__global__ __launch_bounds__(256) void prep_x(const float* __restrict__ X,
                                              uint2* __restrict__ X3) {
  const unsigned T = blockIdx.x * 256 + threadIdx.x;   // 524288
  const int l = T & 63, bt = (T >> 6) & 1, j = (T >> 7) & 2047, bq = (int)(T >> 18);
  const int b = bq * 32 + bt * 16 + (l & 15);
  const float4 src = ((const float4*)X)[((size_t)b * JJ + j) * 4 + (l >> 4)];
  Pack2 a, bb;
  a.h[0] = (_Float16)src.x; a.h[1] = (_Float16)src.y;
  bb.h[0] = (_Float16)src.z; bb.h[1] = (_Float16)src.w;
  X3[T] = make_uint2(a.u, bb.u);
}

// MFMA routing pass, c-major GEMM: per j, C[co][b] = W_j[co][i] x x[b][i].
// Grid NJT*2 blocks of 1024 (16 waves), 1 block/CU. Block: 32 b (bq half) x
// all 1024 co. Wave w owns c in {2w, 2w+1} = ct tiles 4w..4w+3, b-tiles bt 0,1
// -> 8 MFMA(16x16x16)/j. Lane l = g*16 + t: D col = t -> b, D row = 4g+r -> co.
// Logit (HAVE_V): per lane 8 o's in-register -> 8 fma + 2 shuffles; softmax via
// lbuf (one write + row-softmax + coef reads). Triple-buffered W slabs, counted
// vmcnt(2), raw s_barrier with lgkm-only waits.
template<bool HAVE_V>
__global__ __launch_bounds__(1024, 1) void route_mfma(
    const uint4* __restrict__ X3, const uint4* __restrict__ W2,
    const float* __restrict__ vsum, float* __restrict__ partial)
{
  __shared__ uint4 wbuf[3][2048];   // 3 x 32KB W slabs (A-frags, 64 ct x 64 lanes x 8B)
  __shared__ uint4 xbuf[1024];      // 16KB x B-frags: 16 j x 2 bt x 64 lanes x 8B
  __shared__ float lbuf[32 * 33];   // 32 b-rows x 32 c (+1 pad)

  const int jt   = blockIdx.x & (NJT - 1);
  const int bq   = blockIdx.x >> 7;
  const int tid  = threadIdx.x;
  const int w    = tid >> 6;
  const int lane = tid & 63;
  const int g    = lane >> 4;
  const int t    = lane & 15;

  // vsum[b][c][o] for this lane's (2c x 2bt x 8o), packed f16 pairs (16 VGPR).
  unsigned vsh[2][2][2][2];   // [cc][bt][hh][rp]
  if (HAVE_V) {
#pragma unroll
    for (int cc = 0; cc < 2; ++cc)
#pragma unroll
      for (int bt = 0; bt < 2; ++bt)
#pragma unroll
        for (int hh = 0; hh < 2; ++hh)
#pragma unroll
          for (int rp = 0; rp < 2; ++rp) {
            const float* vp = vsum + (size_t)(bq * 32 + bt * 16 + t) * CO
                            + (2 * w + cc) * OO + hh * 16 + 4 * g + 2 * rp;
            Pack2 p; p.h[0] = (_Float16)vp[0]; p.h[1] = (_Float16)vp[1];
            vsh[cc][bt][hh][rp] = p.u;
          }
  }

  const uint4* wsrc = W2 + (size_t)jt * TJ * 2048;   // 16B units, 2048/j

#define STAGEW(bufidx, slab) do {                                                 \
    const uint4* sp_ = wsrc + (size_t)(slab) * 2048 + tid;                        \
    uint4* dp_ = &wbuf[bufidx][tid];                                              \
    _Pragma("unroll")                                                             \
    for (int r_ = 0; r_ < 2; ++r_)                                                \
      __builtin_amdgcn_global_load_lds(                                           \
          (const __attribute__((address_space(1))) void*)(sp_ + r_ * 1024),       \
          (__attribute__((address_space(3))) void*)(dp_ + r_ * 1024), 16, 0, 0);  \
  } while (0)

  // prologue: x B-frags (16 KB, 1 instr/thread) + first two W slabs
  {
    const uint4* xs = X3 + ((size_t)bq * JJ + jt * TJ) * 64 + tid;   // 16B units
    __builtin_amdgcn_global_load_lds(
        (const __attribute__((address_space(1))) void*)xs,
        (__attribute__((address_space(3))) void*)&xbuf[tid], 16, 0, 0);
  }
  STAGEW(0, 0);
  STAGEW(1, 1);

  f32x4 acc[4][2];
#pragma unroll
  for (int k = 0; k < 4; ++k)
#pragma unroll
    for (int bt = 0; bt < 2; ++bt) acc[k][bt] = f32x4{0.f, 0.f, 0.f, 0.f};

  int bcur = 0;
  for (int jj = 0; jj < TJ; ++jj) {
    if (jj == TJ - 1) asm volatile("s_waitcnt vmcnt(0) lgkmcnt(0)" ::: "memory");
    else              asm volatile("s_waitcnt vmcnt(2) lgkmcnt(0)" ::: "memory");
    SCHED_FENCE();
    __builtin_amdgcn_s_barrier();
    if (jj + 2 < TJ) {
      const int bstg = (bcur == 0) ? 2 : bcur - 1;   // (jj+2) % 3
      STAGEW(bstg, jj + 2);
    }

    const uint2* wb2 = (const uint2*)wbuf[bcur];
    const uint2* xb2 = (const uint2*)xbuf;

    f16x4 bf[2];
#pragma unroll
    for (int bt = 0; bt < 2; ++bt)
      bf[bt] = __builtin_bit_cast(f16x4, xb2[(jj * 2 + bt) * 64 + lane]);
    f16x4 af[4];
#pragma unroll
    for (int k = 0; k < 4; ++k)
      af[k] = __builtin_bit_cast(f16x4, wb2[(w * 4 + k) * 64 + lane]);

    f32x4 uh[4][2];
#pragma unroll
    for (int k = 0; k < 4; ++k)
#pragma unroll
      for (int bt = 0; bt < 2; ++bt) {
        if (HAVE_V) uh[k][bt] = MFMA16(af[k], bf[bt], (f32x4{0.f, 0.f, 0.f, 0.f}));
        else        acc[k][bt] = MFMA16(af[k], bf[bt], acc[k][bt]);
      }

    if (HAVE_V) {
      // logit[b][c] partials over this lane's 8 o's, then sum over g (xor16/32)
      float lp[2][2];
#pragma unroll
      for (int cc = 0; cc < 2; ++cc)
#pragma unroll
        for (int bt = 0; bt < 2; ++bt) {
          float s = 0.f;
#pragma unroll
          for (int hh = 0; hh < 2; ++hh)
#pragma unroll
            for (int rp = 0; rp < 2; ++rp) {
              Pack2 p; p.u = vsh[cc][bt][hh][rp];
              s = fmaf(uh[2 * cc + hh][bt][2 * rp],     (float)p.h[0], s);
              s = fmaf(uh[2 * cc + hh][bt][2 * rp + 1], (float)p.h[1], s);
            }
          s += __shfl_xor(s, 16);
          s += __shfl_xor(s, 32);
          lp[cc][bt] = s;
        }
      // each lane writes combo (cc = g>>1, bt = g&1) -> static-index select
      {
        const float hi = (g & 1) ? lp[1][1] : lp[1][0];
        const float lo = (g & 1) ? lp[0][1] : lp[0][0];
        const float val = (g >> 1) ? hi : lo;
        lbuf[((g & 1) * 16 + t) * 33 + 2 * w + (g >> 1)] = val;
      }
      asm volatile("s_waitcnt lgkmcnt(0)" ::: "memory");
      SCHED_FENCE();
      __builtin_amdgcn_s_barrier();

      // row softmax (no max-sub: |logit| <= |vsum||uh| ~ 20, exp safe in f32);
      // wave w owns rows 2w, 2w+1 (32 lanes per row).
      {
        const int row = 2 * w + (lane >> 5);
        const int cc2 = lane & 31;
        float e = __expf(lbuf[row * 33 + cc2]);
        float den = e;
        den += __shfl_xor(den, 1);  den += __shfl_xor(den, 2);
        den += __shfl_xor(den, 4);  den += __shfl_xor(den, 8);
        den += __shfl_xor(den, 16);
        lbuf[row * 33 + cc2] = e / den;
      }
      asm volatile("s_waitcnt lgkmcnt(0)" ::: "memory");
      SCHED_FENCE();
      __builtin_amdgcn_s_barrier();

      float cf[2][2];
#pragma unroll
      for (int cc = 0; cc < 2; ++cc)
#pragma unroll
        for (int bt = 0; bt < 2; ++bt)
          cf[cc][bt] = lbuf[(bt * 16 + t) * 33 + 2 * w + cc];
#pragma unroll
      for (int k = 0; k < 4; ++k)
#pragma unroll
        for (int bt = 0; bt < 2; ++bt)
#pragma unroll
          for (int r = 0; r < 4; ++r)
            acc[k][bt][r] = fmaf(cf[k >> 1][bt], uh[k][bt][r], acc[k][bt][r]);
    }
    bcur = (bcur == 2) ? 0 : bcur + 1;
  }
#undef STAGEW

  // D layout: col = t -> b, rows = 4g + r -> co: acc[k][bt] is 4 consecutive co
  // -> float4 store; per b-row a wave covers 256B contiguous.
  const float cs = HAVE_V ? 1.f : 0.03125f;
#pragma unroll
  for (int k = 0; k < 4; ++k)
#pragma unroll
    for (int bt = 0; bt < 2; ++bt) {
      const int b  = bq * 32 + bt * 16 + t;
      const int co = (4 * w + k) * 16 + 4 * g;
      float4 v = make_float4(acc[k][bt][0] * cs, acc[k][bt][1] * cs,
                             acc[k][bt][2] * cs, acc[k][bt][3] * cs);
      *(float4*)(partial + ((size_t)jt * BB + b) * CO + co) = v;
    }
}

// ---------------- f32 fallback route (proven R2/R4 path) ----------------
template<bool HAVE_V>
__global__ __launch_bounds__(256, 1) void route_f32(
    const float* __restrict__ X, const float* __restrict__ W,
    const float* __restrict__ vsum, float* __restrict__ partial)
{
  const int jt   = blockIdx.x & 63;
  const int bq   = blockIdx.x >> 6;
  const int tid  = threadIdx.x;
  const int wave = tid >> 6;
  const int lane = tid & 63;
  const int c    = lane & 31;
  const int o0   = (lane >> 5) << 4;
  const int b0   = bq * 16 + wave * 4;

  float acc[4][16];
#pragma unroll
  for (int bl = 0; bl < 4; ++bl)
#pragma unroll
    for (int ol = 0; ol < 16; ++ol) acc[bl][ol] = 0.f;

  const float* wbase = W + ((size_t)c * JJ * OO + (size_t)o0) * DI;

  for (int jj = 0; jj < 32; ++jj) {
    const int j = jt * 32 + jj;
    float xf[4][16];
#pragma unroll
    for (int bl = 0; bl < 4; ++bl) {
      const float4* xpt = (const float4*)(X + ((size_t)(b0 + bl) * JJ + j) * DI);
#pragma unroll
      for (int q = 0; q < 4; ++q) {
        float4 x4 = xpt[q];
        xf[bl][4*q+0] = x4.x; xf[bl][4*q+1] = x4.y;
        xf[bl][4*q+2] = x4.z; xf[bl][4*q+3] = x4.w;
      }
    }
    const float4* wp = (const float4*)(wbase + (size_t)j * OO * DI);
    float tv[4][16];
#pragma unroll
    for (int ol = 0; ol < 16; ++ol) {
      float wf[16];
#pragma unroll
      for (int q = 0; q < 4; ++q) {
        float4 w4 = wp[4*ol + q];
        wf[4*q+0] = w4.x; wf[4*q+1] = w4.y;
        wf[4*q+2] = w4.z; wf[4*q+3] = w4.w;
      }
#pragma unroll
      for (int bl = 0; bl < 4; ++bl) {
        float tt = 0.f;
#pragma unroll
        for (int i = 0; i < 16; ++i) tt = fmaf(wf[i], xf[bl][i], tt);
        if (!HAVE_V) acc[bl][ol] += tt;
        else         tv[bl][ol] = tt;
      }
    }
    if (HAVE_V) {
#pragma unroll
      for (int bl = 0; bl < 4; ++bl) {
        float dsum = 0.f;
        const float4* vp = (const float4*)(vsum + (size_t)(b0 + bl) * CO + c * OO + o0);
#pragma unroll
        for (int q = 0; q < 4; ++q) {
          float4 v4 = vp[q];
          dsum = fmaf(v4.x, tv[bl][4*q+0], dsum);
          dsum = fmaf(v4.y, tv[bl][4*q+1], dsum);
          dsum = fmaf(v4.z, tv[bl][4*q+2], dsum);
          dsum = fmaf(v4.w, tv[bl][4*q+3], dsum);
        }
        dsum += __shfl_xor(dsum, 32);
        float mm = dsum;
#pragma unroll
        for (int s = 16; s >= 1; s >>= 1) mm = fmaxf(mm, __shfl_xor(mm, s));
        float e = __expf(dsum - mm);
        float den = e;
#pragma unroll
        for (int s = 16; s >= 1; s >>= 1) den += __shfl_xor(den, s);
        float coef = e / den;
#pragma unroll
        for (int ol = 0; ol < 16; ++ol)
          acc[bl][ol] = fmaf(coef, tv[bl][ol], acc[bl][ol]);
      }
    }
  }
  const float cs = HAVE_V ? 1.f : 0.03125f;
#pragma unroll
  for (int bl = 0; bl < 4; ++bl) {
    float* pp = partial + ((size_t)jt * BB + (b0 + bl)) * CO + c * OO + o0;
#pragma unroll
    for (int q = 0; q < 4; ++q) {
      float4 w4 = make_float4(acc[bl][4*q+0]*cs, acc[bl][4*q+1]*cs,
                              acc[bl][4*q+2]*cs, acc[bl][4*q+3]*cs);
      ((float4*)pp)[q] = w4;
    }
  }
}

// Sum NJT j-tile partials -> s[b,c,o]; squash over o; maintain vsum / write out.
template<int NJTR>
__global__ __launch_bounds__(256, 1) void reduce_squash(
    const float* __restrict__ partial, float* __restrict__ vsum,
    float* __restrict__ out, int mode)   // 0: vsum = v; 1: vsum += v; 2: out = v
{
  const int idx = blockIdx.x * 256 + threadIdx.x;   // = b*CO + c*OO + o
  float s0 = 0.f, s1 = 0.f, s2 = 0.f, s3 = 0.f;
#pragma unroll 4
  for (int nt = 0; nt < NJTR; nt += 4) {
    s0 += partial[(size_t)(nt + 0) * (BB * CO) + idx];
    s1 += partial[(size_t)(nt + 1) * (BB * CO) + idx];
    s2 += partial[(size_t)(nt + 2) * (BB * CO) + idx];
    s3 += partial[(size_t)(nt + 3) * (BB * CO) + idx];
  }
  float s = (s0 + s1) + (s2 + s3);
  float s2m = s * s;
#pragma unroll
  for (int mk = 16; mk >= 1; mk >>= 1) s2m += __shfl_xor(s2m, mk);
  float scale = s2m / ((1.f + s2m) * sqrtf(s2m + 1e-7f));
  float v = scale * s;
  if (mode == 2)      out[idx] = v;
  else if (mode == 1) vsum[idx] += v;
  else                vsum[idx] = v;
}

static void run_mfma(const float* X, const float* W, float* out,
                     void* d_ws, hipStream_t stream)
{
  uint2* W2      = (uint2*)d_ws;
  uint2* X3      = (uint2*)((char*)d_ws + W2_BYTES);
  float* partial = (float*)((char*)d_ws + W2_BYTES + X3_BYTES);
  float* vsum    = partial + (size_t)NJT * BB * CO;
  const int grid  = NJT * 2;         // 256 blocks of 1024
  const int rgrid = BB * CO / 256;

  prep_w<<<JJ, 256, 0, stream>>>(W, W2);
  prep_x<<<2048, 256, 0, stream>>>(X, X3);

  route_mfma<false><<<grid, 1024, 0, stream>>>((const uint4*)X3, (const uint4*)W2, nullptr, partial);
  reduce_squash<NJT><<<rgrid, 256, 0, stream>>>(partial, vsum, nullptr, 0);

  route_mfma<true><<<grid, 1024, 0, stream>>>((const uint4*)X3, (const uint4*)W2, vsum, partial);
  reduce_squash<NJT><<<rgrid, 256, 0, stream>>>(partial, vsum, nullptr, 1);

  route_mfma<true><<<grid, 1024, 0, stream>>>((const uint4*)X3, (const uint4*)W2, vsum, partial);
  reduce_squash<NJT><<<rgrid, 256, 0, stream>>>(partial, vsum, out, 2);
}

static void run_f32_fallback(const float* X, const float* W, float* out,
                             void* d_ws, hipStream_t stream)
{
  float* partial = (float*)d_ws;
  float* vsum    = partial + (size_t)64 * BB * CO;
  const int grid  = 64 * 4;
  const int rgrid = BB * CO / 256;

  route_f32<false><<<grid, 256, 0, stream>>>(X, W, nullptr, partial);
  reduce_squash<64><<<rgrid, 256, 0, stream>>>(partial, vsum, nullptr, 0);
  route_f32<true><<<grid, 256, 0, stream>>>(X, W, vsum, partial);
  reduce_squash<64><<<rgrid, 256, 0, stream>>>(partial, vsum, nullptr, 1);
  route_f32<true><<<grid, 256, 0, stream>>>(X, W, vsum, partial);
  reduce_squash<64><<<rgrid, 256, 0, stream>>>(partial, vsum, out, 2);
}

extern "C" void kernel_launch(void* const* d_in, const int* in_sizes, int n_in,
                              void* d_out, int out_size, void* d_ws, size_t ws_size,
                              hipStream_t stream) {
  (void)in_sizes; (void)n_in; (void)out_size;
  const float* X = (const float*)d_in[0];   // x [64,2048,16] f32
  const float* W = (const float*)d_in[1];   // W [32,2048,32,16] f32
  float* out = (float*)d_out;               // v [64,32,32] f32

  const size_t need = W2_BYTES + X3_BYTES
                    + (size_t)NJT * BB * CO * 4 + (size_t)BB * CO * 4;
  if (ws_size >= need) run_mfma(X, W, out, d_ws, stream);
  else                 run_f32_fallback(X, W, out, d_ws, stream);
}